// Round 3
// baseline (198.572 us; speedup 1.0000x reference)
//
#include <hip/hip_runtime.h>

// CombinedLoss = 0.7 * class-weighted Dice + 0.3 * Sobel-boundary BCE
// [B=8,C=4,H=512,W=512] fp32. Binary boundary BCE == 100 * mismatch-rate.
// Occupancy-first design: 2 cols/lane (128-col quarter-strips), R_=4 rows/task,
// 4-slot rolling row window, targets bit-packed (Sobel-on-targets in exact int
// arithmetic), wave-edge halos via uniform scalar loads. <=64 VGPR target
// (__launch_bounds__(512,8)) -> 8 waves/SIMD. 1024 blocks x 8 waves, each wave
// runs 2 tasks (adjacent column quarters) -> 16 KB partials (known-safe ws size).

#define H_ 512
#define W_ 512
#define CW 128          // cols per task
#define NIMG 32
#define NPIXF 8388608.0f
#define R_ 4            // output rows per task
#define NBLK 1024       // 32 img * 32 blocks; block = 4 rowsegs x 2 quarter-pair waves

__device__ __forceinline__ float sigf(float x) {
    return __builtin_amdgcn_rcpf(1.f + __expf(-x));
}

__launch_bounds__(512, 8)
__global__ void fused_loss_kernel(const float* __restrict__ logits,
                                  const float* __restrict__ targets,
                                  float4* __restrict__ part) {
    const int tid  = threadIdx.x;
    const int wid  = tid >> 6, lane = tid & 63;
    const int bx   = blockIdx.x;
    const int img  = bx >> 5;                        // 32 blocks per image
    const int rs   = ((bx & 31) << 2) | (wid >> 1);  // rowseg 0..127
    const int y0   = rs << 2;
    const int qb   = (wid & 1) << 1;                 // quarter base: 0 or 2

    const float* Li = logits  + (size_t)img * (H_ * W_);
    const float* Ti = targets + (size_t)img * (H_ * W_);

    float li = 0.f, lp = 0.f;
    int lt = 0, mi = 0;

    #pragma unroll
    for (int rep = 0; rep < 2; ++rep) {
        const int q    = qb + rep;
        const int c0   = q << 7;
        const int cl   = c0 + (lane << 1);
        const int hasL = (c0 > 0);
        const int hasR = (c0 + CW < W_);
        const int colL = hasL ? c0 - 1 : 0;      // clamped (result masked)
        const int colR = hasR ? c0 + CW : W_ - 1;

        float p[4][2];           // sigmoid window, 2 cols/lane
        float pHL[4], pHR[4];    // wave-uniform halo columns (sigmoid)
        int   tm[4];             // target bits: b0=col-1, b1=col0, b2=col1, b3=col2

        auto loadrow = [&](int gy, int s) {
            if ((unsigned)gy < (unsigned)H_) {
                const float2 va = *(const float2*)(Li + gy * W_ + cl);
                const float2 vb = *(const float2*)(Ti + gy * W_ + cl);
                p[s][0] = sigf(va.x); p[s][1] = sigf(va.y);
                const float hl = Li[gy * W_ + colL];
                const float hr = Li[gy * W_ + colR];
                pHL[s] = hasL ? sigf(hl) : 0.f;
                pHR[s] = hasR ? sigf(hr) : 0.f;
                const float tl = Ti[gy * W_ + colL];
                const float tr = Ti[gy * W_ + colR];
                const int m  = (vb.x != 0.f ? 1 : 0) | (vb.y != 0.f ? 2 : 0);
                const int up = __shfl_up(m, 1, 64);    // neighbor col1 -> our col-1
                const int dn = __shfl_down(m, 1, 64);  // neighbor col0 -> our col2
                const int bl = (lane == 0)  ? ((hasL && tl != 0.f) ? 1 : 0) : ((up >> 1) & 1);
                const int br = (lane == 63) ? ((hasR && tr != 0.f) ? 1 : 0) : (dn & 1);
                tm[s] = bl | (m << 1) | (br << 3);
            } else {
                p[s][0] = 0.f; p[s][1] = 0.f; pHL[s] = 0.f; pHR[s] = 0.f; tm[s] = 0;
            }
        };

        // rows y0-1 .. y0+4 ; slot = gy & 3
        loadrow(y0 - 1, 3);
        loadrow(y0,     0);
        loadrow(y0 + 1, 1);

        #pragma unroll
        for (int i = 0; i < R_; ++i) {
            if (i < R_ - 1) loadrow(y0 + 2 + i, (2 + i) & 3);   // depth-1 prefetch
            const int sA = (i + 3) & 3, sB = i & 3, sC = (i + 1) & 3;

            // ---- prediction (float) Sobel ----
            const float Tc0 = (p[sA][0] + p[sC][0]) + 2.f * p[sB][0];
            const float Tc1 = (p[sA][1] + p[sC][1]) + 2.f * p[sB][1];
            const float Sc0 = p[sC][0] - p[sA][0];
            const float Sc1 = p[sC][1] - p[sA][1];
            const float THL = (pHL[sA] + pHL[sC]) + 2.f * pHL[sB];
            const float SHL = pHL[sC] - pHL[sA];
            const float THR = (pHR[sA] + pHR[sC]) + 2.f * pHR[sB];
            const float SHR = pHR[sC] - pHR[sA];
            float TL = __shfl_up(Tc1, 1, 64), SL = __shfl_up(Sc1, 1, 64);
            float TR = __shfl_down(Tc0, 1, 64), SR = __shfl_down(Sc0, 1, 64);
            if (lane == 0)  { TL = THL; SL = SHL; }
            if (lane == 63) { TR = THR; SR = SHR; }

            const float gx0 = Tc1 - TL, gy0 = (SL + Sc1) + 2.f * Sc0;
            const int pb0 = (gx0 * gx0 + gy0 * gy0) > 0.25f;
            const float gx1 = TR - Tc0, gy1 = (Sc0 + SR) + 2.f * Sc1;
            const int pb1 = (gx1 * gx1 + gy1 * gy1) > 0.25f;

            // ---- target (bit) Sobel, exact integer ----
            const int mA = tm[sA], mB = tm[sB], mC = tm[sC];
            const int a0 = mA & 1, a1 = (mA >> 1) & 1, a2 = (mA >> 2) & 1, a3 = (mA >> 3) & 1;
            const int b0 = mB & 1, b1 = (mB >> 1) & 1, b2 = (mB >> 2) & 1, b3 = (mB >> 3) & 1;
            const int e0 = mC & 1, e1 = (mC >> 1) & 1, e2 = (mC >> 2) & 1, e3 = (mC >> 3) & 1;
            const int hx0 = (a2 + 2 * b2 + e2) - (a0 + 2 * b0 + e0);
            const int hy0 = (e0 - a0) + 2 * (e1 - a1) + (e2 - a2);
            const int tb0 = ((hx0 | hy0) != 0);
            const int hx1 = (a3 + 2 * b3 + e3) - (a1 + 2 * b1 + e1);
            const int hy1 = (e1 - a1) + 2 * (e2 - a2) + (e3 - a3);
            const int tb1 = ((hx1 | hy1) != 0);

            mi += (pb0 ^ tb0) + (pb1 ^ tb1);

            // ---- Dice partials (center row only) ----
            lp += p[sB][0] + p[sB][1];
            lt += b1 + b2;
            li += (b1 ? p[sB][0] : 0.f) + (b2 ? p[sB][1] : 0.f);
        }
    }

    // pack the two small int sums into one reduction channel (max wave sum 1024 each)
    int pk = mi | (lt << 16);
    #pragma unroll
    for (int off = 32; off > 0; off >>= 1) {
        li += __shfl_down(li, off, 64);
        lp += __shfl_down(lp, off, 64);
        pk += __shfl_down(pk, off, 64);
    }
    __shared__ float red[8][4];
    if (lane == 0) {
        red[wid][0] = li;
        red[wid][1] = lp;
        red[wid][2] = (float)(pk >> 16);      // sum t
        red[wid][3] = (float)(pk & 0xFFFF);   // mismatches
    }
    __syncthreads();
    if (tid == 0) {
        float a = 0.f, b = 0.f, c = 0.f, d = 0.f;
        #pragma unroll
        for (int w = 0; w < 8; ++w) {
            a += red[w][0]; b += red[w][1]; c += red[w][2]; d += red[w][3];
        }
        part[bx] = make_float4(a, b, c, d);
    }
}

__global__ void finalize_kernel(const float4* __restrict__ part,
                                const float* __restrict__ cw,
                                float* __restrict__ out) {
    __shared__ float s_i[NIMG], s_p[NIMG], s_t[NIMG], s_m[NIMG];
    const int tid = threadIdx.x;           // 1024 threads, one per block-partial
    float4 v = part[tid];
    float vi = v.x, vp = v.y, vt = v.z, vm = v.w;
    #pragma unroll
    for (int off = 16; off > 0; off >>= 1) {   // 32 partials per image, segmented
        vi += __shfl_down(vi, off, 32);
        vp += __shfl_down(vp, off, 32);
        vt += __shfl_down(vt, off, 32);
        vm += __shfl_down(vm, off, 32);
    }
    if ((tid & 31) == 0) {
        const int img = tid >> 5;
        s_i[img] = vi; s_p[img] = vp; s_t[img] = vt; s_m[img] = vm;
    }
    __syncthreads();
    if (tid == 0) {
        float mm = 0.f;
        for (int i = 0; i < NIMG; ++i) mm += s_m[i];
        float wsum = 0.f, dl = 0.f;
        for (int c = 0; c < 4; ++c) {
            float md = 0.f;
            for (int b = 0; b < 8; ++b) {
                const int id = b * 4 + c;
                md += (2.f * s_i[id] + 1.f) / (s_p[id] + s_t[id] + 1.f);
            }
            md *= 0.125f;
            dl += cw[c] * (1.f - md);
            wsum += cw[c];
        }
        out[0] = 0.7f * (dl / wsum) + 0.3f * (100.f * mm / NPIXF);
    }
}

extern "C" void kernel_launch(void* const* d_in, const int* in_sizes, int n_in,
                              void* d_out, int out_size, void* d_ws, size_t ws_size,
                              hipStream_t stream) {
    const float* logits  = (const float*)d_in[0];
    const float* targets = (const float*)d_in[1];
    const float* cw      = (const float*)d_in[2];
    float* out = (float*)d_out;
    float4* part = (float4*)d_ws;   // NBLK * 16 B = 16 KB (validated in prior rounds)

    fused_loss_kernel<<<NBLK, 512, 0, stream>>>(logits, targets, part);
    finalize_kernel<<<1, 1024, 0, stream>>>(part, cw, out);
}

// Round 5
// 104.870 us; speedup vs baseline: 1.8935x; 1.8935x over previous
//
#include <hip/hip_runtime.h>

// CombinedLoss = 0.7 * class-weighted Dice + 0.3 * Sobel-boundary BCE
// [B=8,C=4,H=512,W=512] fp32. Binary boundary BCE == 100 * mismatch-rate.
// Full-row-strip waves (512 cols, 8 cols/lane, 4x float4/row = max MLP, no scalar
// loads), bit-packed target Sobel (exact int), sliding column sums (no Tc/Sc
// arrays), R_=4 rows/task. 4096 tasks = 1024 blocks x 4 waves = 4 waves/SIMD,
// single residency round. Partials: 16 KB (validated ws size).

#define H_ 512
#define W_ 512
#define NIMG 32
#define NPIXF 8388608.0f
#define R_ 4            // output rows per wave
#define NBLK 1024       // 4096 tasks / 4 waves per block

__device__ __forceinline__ float sigf(float x) {
    return __builtin_amdgcn_rcpf(1.f + __expf(-x));
}

__launch_bounds__(256, 4)
__global__ void fused_loss_kernel(const float* __restrict__ logits,
                                  const float* __restrict__ targets,
                                  float4* __restrict__ part) {
    const int tid  = threadIdx.x;
    const int wid  = tid >> 6, lane = tid & 63;
    const int task = (blockIdx.x << 2) | wid;   // 4096 tasks
    const int img  = task >> 7;                 // 128 rowsegs per image
    const int y0   = (task & 127) << 2;

    const float* Lp = logits  + (size_t)img * (H_ * W_) + (lane << 3);
    const float* Tp = targets + (size_t)img * (H_ * W_) + (lane << 3);

    float p[4][8];   // sigmoid row window, 8 cols/lane
    int   tm[4];     // target bits: bit0 = left halo, bits1..8 = cols, bit9 = right halo

    auto loadrow = [&](int gy, int s) {
        if ((unsigned)gy < (unsigned)H_) {
            const float4 va = *(const float4*)(Lp + (gy << 9));
            const float4 vb = *(const float4*)(Lp + (gy << 9) + 4);
            const float4 vc = *(const float4*)(Tp + (gy << 9));
            const float4 vd = *(const float4*)(Tp + (gy << 9) + 4);
            p[s][0] = sigf(va.x); p[s][1] = sigf(va.y);
            p[s][2] = sigf(va.z); p[s][3] = sigf(va.w);
            p[s][4] = sigf(vb.x); p[s][5] = sigf(vb.y);
            p[s][6] = sigf(vb.z); p[s][7] = sigf(vb.w);
            int m8 = (vc.x != 0.f ? 1   : 0) | (vc.y != 0.f ? 2   : 0)
                   | (vc.z != 0.f ? 4   : 0) | (vc.w != 0.f ? 8   : 0)
                   | (vd.x != 0.f ? 16  : 0) | (vd.y != 0.f ? 32  : 0)
                   | (vd.z != 0.f ? 64  : 0) | (vd.w != 0.f ? 128 : 0);
            const int up = __shfl_up(m8, 1, 64);
            const int dn = __shfl_down(m8, 1, 64);
            const int bl = (lane == 0)  ? 0 : ((up >> 7) & 1);
            const int br = (lane == 63) ? 0 : (dn & 1);
            tm[s] = bl | (m8 << 1) | (br << 9);
        } else {
            #pragma unroll
            for (int k = 0; k < 8; ++k) p[s][k] = 0.f;
            tm[s] = 0;
        }
    };

    // rows y0-1 .. y0+4 ; slot = gy & 3 (y0 is a multiple of 4)
    loadrow(y0 - 1, 3);
    loadrow(y0,     0);
    loadrow(y0 + 1, 1);

    float li = 0.f, lp = 0.f;
    int lt = 0, mi = 0;

    #pragma unroll
    for (int i = 0; i < R_; ++i) {
        if (i < R_ - 1) loadrow(y0 + 2 + i, (2 + i) & 3);   // depth-1 prefetch
        const int sA = (i + 3) & 3, sB = i & 3, sC = (i + 1) & 3;

        // ---- prediction column sums (vertical [1,2,1] and [-1,0,1]) ----
        #define CS_(T, S, k) { const float a_ = p[sA][k], b_ = p[sB][k], c_ = p[sC][k]; \
                               T = (a_ + c_) + 2.f * b_; S = c_ - a_; }
        float T7, S7, T0, S0;
        CS_(T7, S7, 7);
        CS_(T0, S0, 0);
        float TL = __shfl_up(T7, 1, 64),   SL = __shfl_up(S7, 1, 64);
        float TR = __shfl_down(T0, 1, 64), SR = __shfl_down(S0, 1, 64);
        if (lane == 0)  { TL = 0.f; SL = 0.f; }
        if (lane == 63) { TR = 0.f; SR = 0.f; }

        // ---- target column sums from bits (col j <-> bit j+1) ----
        const int mA = tm[sA], mB = tm[sB], mC = tm[sC];
        #define TS_(tt, st, bit) { const int a_ = (mA >> (bit)) & 1, b_ = (mB >> (bit)) & 1, \
                                   c_ = (mC >> (bit)) & 1; tt = a_ + (b_ << 1) + c_; st = c_ - a_; }
        const int m8c = (mB >> 1) & 0xFF;
        lt += __popc(m8c);

        float Tm = TL, Sm = SL, Tk = T0, Sk = S0;
        int ttm, stm, ttk, stk;
        TS_(ttm, stm, 0);
        TS_(ttk, stk, 1);

        #pragma unroll
        for (int k = 0; k < 8; ++k) {
            float Tp_, Sp_;
            if (k == 6)      { Tp_ = T7; Sp_ = S7; }
            else if (k == 7) { Tp_ = TR; Sp_ = SR; }
            else             CS_(Tp_, Sp_, k + 1);
            int ttp, stp;
            TS_(ttp, stp, k + 2);

            const float gx = Tp_ - Tm;
            const float gv = (Sm + Sp_) + 2.f * Sk;
            const int pb = (gx * gx + gv * gv) > 0.25f;

            const int hx = ttp - ttm;
            const int hv = stm + stp + (stk << 1);
            const int tb = ((hx | hv) != 0);

            mi += pb ^ tb;

            const float pv = p[sB][k];
            lp += pv;
            li += ((m8c >> k) & 1) ? pv : 0.f;

            Tm = Tk; Sm = Sk; Tk = Tp_; Sk = Sp_;
            ttm = ttk; stm = stk; ttk = ttp; stk = stp;
        }
        #undef CS_
        #undef TS_
    }

    // pack the two small int sums into one reduction channel (wave sums <= 2048)
    int pk = mi | (lt << 16);
    #pragma unroll
    for (int off = 32; off > 0; off >>= 1) {
        li += __shfl_down(li, off, 64);
        lp += __shfl_down(lp, off, 64);
        pk += __shfl_down(pk, off, 64);
    }
    __shared__ float red[4][4];
    if (lane == 0) {
        red[wid][0] = li;
        red[wid][1] = lp;
        red[wid][2] = (float)(pk >> 16);      // sum t
        red[wid][3] = (float)(pk & 0xFFFF);   // mismatches
    }
    __syncthreads();
    if (tid == 0) {
        float a = 0.f, b = 0.f, c = 0.f, d = 0.f;
        #pragma unroll
        for (int w = 0; w < 4; ++w) {
            a += red[w][0]; b += red[w][1]; c += red[w][2]; d += red[w][3];
        }
        part[blockIdx.x] = make_float4(a, b, c, d);
    }
}

__global__ void finalize_kernel(const float4* __restrict__ part,
                                const float* __restrict__ cw,
                                float* __restrict__ out) {
    __shared__ float s_i[NIMG], s_p[NIMG], s_t[NIMG], s_m[NIMG];
    const int tid = threadIdx.x;           // 1024 threads, one per block-partial
    float4 v = part[tid];
    float vi = v.x, vp = v.y, vt = v.z, vm = v.w;
    #pragma unroll
    for (int off = 16; off > 0; off >>= 1) {   // 32 partials per image, segmented
        vi += __shfl_down(vi, off, 32);
        vp += __shfl_down(vp, off, 32);
        vt += __shfl_down(vt, off, 32);
        vm += __shfl_down(vm, off, 32);
    }
    if ((tid & 31) == 0) {
        const int img = tid >> 5;
        s_i[img] = vi; s_p[img] = vp; s_t[img] = vt; s_m[img] = vm;
    }
    __syncthreads();
    if (tid == 0) {
        float mm = 0.f;
        for (int i = 0; i < NIMG; ++i) mm += s_m[i];
        float wsum = 0.f, dl = 0.f;
        for (int c = 0; c < 4; ++c) {
            float md = 0.f;
            for (int b = 0; b < 8; ++b) {
                const int id = b * 4 + c;
                md += (2.f * s_i[id] + 1.f) / (s_p[id] + s_t[id] + 1.f);
            }
            md *= 0.125f;
            dl += cw[c] * (1.f - md);
            wsum += cw[c];
        }
        out[0] = 0.7f * (dl / wsum) + 0.3f * (100.f * mm / NPIXF);
    }
}

extern "C" void kernel_launch(void* const* d_in, const int* in_sizes, int n_in,
                              void* d_out, int out_size, void* d_ws, size_t ws_size,
                              hipStream_t stream) {
    const float* logits  = (const float*)d_in[0];
    const float* targets = (const float*)d_in[1];
    const float* cw      = (const float*)d_in[2];
    float* out = (float*)d_out;
    float4* part = (float4*)d_ws;   // NBLK * 16 B = 16 KB (validated size)

    fused_loss_kernel<<<NBLK, 256, 0, stream>>>(logits, targets, part);
    finalize_kernel<<<1, 1024, 0, stream>>>(part, cw, out);
}